// Round 1
// baseline (142.840 us; speedup 1.0000x reference)
//
#include <hip/hip_runtime.h>
#include <hip/hip_bf16.h>

// RBF Gram matrix: out[i][j] = exp(-||X_i - Y_j||^2), X,Y fp32 [8192][256].
// Strategy: x2/y2 norms (fp32) + bf16 MFMA GEMM for the cross term + fused exp.

#define MROWS 8192
#define NDIM  256
#define BM 128
#define BN 128
#define BK 64

typedef __bf16 bf16x8 __attribute__((ext_vector_type(8)));
typedef float  f32x4  __attribute__((ext_vector_type(4)));

__device__ inline unsigned short f2bf(float f) {
    union { float f; unsigned u; } cv; cv.f = f;
    unsigned u = cv.u;
    unsigned r = u + 0x7fffu + ((u >> 16) & 1u);  // round-to-nearest-even
    return (unsigned short)(r >> 16);
}

// One wave per row: sum of squares of 256 floats (4 per lane as float4).
__global__ __launch_bounds__(256) void rbf_norms(const float* __restrict__ X,
                                                 const float* __restrict__ Y,
                                                 float* __restrict__ x2,
                                                 float* __restrict__ y2) {
    const int gw   = (blockIdx.x * blockDim.x + threadIdx.x) >> 6;
    const int lane = threadIdx.x & 63;
    const float* src = (gw < MROWS) ? X : Y;
    float*       dst = (gw < MROWS) ? x2 : y2;
    const int    row = (gw < MROWS) ? gw : gw - MROWS;

    f32x4 v = *(const f32x4*)(src + (size_t)row * NDIM + lane * 4);
    float s = v[0]*v[0] + v[1]*v[1] + v[2]*v[2] + v[3]*v[3];
#pragma unroll
    for (int off = 32; off > 0; off >>= 1) s += __shfl_xor(s, off);
    if (lane == 0) dst[row] = s;
}

// 128x128 tile per 256-thread block; 4 waves in 2x2, each owns 64x64.
__global__ __launch_bounds__(256, 2) void rbf_gemm(const float* __restrict__ X,
                                                   const float* __restrict__ Y,
                                                   const float* __restrict__ x2,
                                                   const float* __restrict__ y2,
                                                   float* __restrict__ out) {
    __shared__ unsigned short As[BM * BK];  // XOR-swizzled bf16 tiles
    __shared__ unsigned short Bs[BN * BK];

    const int tid  = threadIdx.x;
    const int lane = tid & 63;
    const int wid  = tid >> 6;
    const int wy   = wid >> 1;      // 0..1
    const int wx   = wid & 1;       // 0..1

    const int row0 = blockIdx.y * BM;
    const int col0 = blockIdx.x * BN;

    f32x4 acc[4][4] = {};

    const int lrow = tid >> 4;         // 0..15 (row within a 16-row staging pass)
    const int lcol = (tid & 15) * 4;   // fp32 column within BK

    const int khalf = lane >> 4;       // 0..3 (k-chunk of 8 within K=32)
    const int fr    = lane & 15;       // fragment row/col

    for (int k0 = 0; k0 < NDIM; k0 += BK) {
        // ---- stage A (X rows) and B (Y rows) as bf16 with swizzle ----
#pragma unroll
        for (int p = 0; p < 8; ++p) {
            const int r = p * 16 + lrow;
            const int byte = r * (BK * 2) + lcol * 2;      // row stride 128 B
            const int sw   = byte ^ ((r & 7) << 4);

            f32x4 va = *(const f32x4*)(X + (size_t)(row0 + r) * NDIM + k0 + lcol);
            ushort4 ua;
            ua.x = f2bf(va[0]); ua.y = f2bf(va[1]); ua.z = f2bf(va[2]); ua.w = f2bf(va[3]);
            *(ushort4*)((char*)As + sw) = ua;

            f32x4 vb = *(const f32x4*)(Y + (size_t)(col0 + r) * NDIM + k0 + lcol);
            ushort4 ub;
            ub.x = f2bf(vb[0]); ub.y = f2bf(vb[1]); ub.z = f2bf(vb[2]); ub.w = f2bf(vb[3]);
            *(ushort4*)((char*)Bs + sw) = ub;
        }
        __syncthreads();

        // ---- MFMA over this K-tile (2 steps of K=32) ----
#pragma unroll
        for (int kk = 0; kk < 2; ++kk) {
            bf16x8 af[4], bfr[4];
#pragma unroll
            for (int m = 0; m < 4; ++m) {
                const int r = wy * 64 + m * 16 + fr;
                const int byte = r * (BK * 2) + (kk * 32 + khalf * 8) * 2;
                af[m] = *(const bf16x8*)((const char*)As + (byte ^ ((r & 7) << 4)));
            }
#pragma unroll
            for (int n = 0; n < 4; ++n) {
                const int r = wx * 64 + n * 16 + fr;
                const int byte = r * (BK * 2) + (kk * 32 + khalf * 8) * 2;
                bfr[n] = *(const bf16x8*)((const char*)Bs + (byte ^ ((r & 7) << 4)));
            }
#pragma unroll
            for (int m = 0; m < 4; ++m)
#pragma unroll
                for (int n = 0; n < 4; ++n)
                    acc[m][n] = __builtin_amdgcn_mfma_f32_16x16x32_bf16(
                        af[m], bfr[n], acc[m][n], 0, 0, 0);
        }
        __syncthreads();
    }

    // ---- epilogue: exp(-(x2 + y2 - 2*xy)) ----
    const int ci    = row0 + wy * 64;
    const int cj    = col0 + wx * 64 + fr;
    const int rbase = khalf * 4;   // C/D: row = (lane>>4)*4 + reg, col = lane&15
#pragma unroll
    for (int m = 0; m < 4; ++m) {
#pragma unroll
        for (int r = 0; r < 4; ++r) {
            const int i  = ci + m * 16 + rbase + r;
            const float xi = x2[i];
#pragma unroll
            for (int n = 0; n < 4; ++n) {
                const int j = cj + n * 16;
                float sq = xi + y2[j] - 2.0f * acc[m][n][r];
                sq = fmaxf(sq, 0.0f);
                out[(size_t)i * MROWS + j] = __expf(-sq);
            }
        }
    }
}

extern "C" void kernel_launch(void* const* d_in, const int* in_sizes, int n_in,
                              void* d_out, int out_size, void* d_ws, size_t ws_size,
                              hipStream_t stream) {
    const float* X = (const float*)d_in[0];
    const float* Y = (const float*)d_in[1];
    float* out = (float*)d_out;
    float* x2  = (float*)d_ws;
    float* y2  = x2 + MROWS;

    rbf_norms<<<(2 * MROWS) / (256 / 64), 256, 0, stream>>>(X, Y, x2, y2);

    dim3 grid(MROWS / BN, MROWS / BM);
    rbf_gemm<<<grid, 256, 0, stream>>>(X, Y, x2, y2, out);
}

// Round 2
// 85.079 us; speedup vs baseline: 1.6789x; 1.6789x over previous
//
#include <hip/hip_runtime.h>
#include <hip/hip_bf16.h>

// RBF Gram matrix: out[i][j] = exp(-||X_i - Y_j||^2), X,Y fp32 [8192][256].
// Path A (ws >= 8.5 MB): prep kernel converts X,Y -> bf16 panels + norms;
//   GEMM stages bf16 via global_load_lds (pre-swizzled source), double-buffered
//   with counted vmcnt, fused exp epilogue.
// Path B (fallback): round-1 fp32-staging version.

#define MROWS 8192
#define NDIM  256
#define BM 128
#define BN 128
#define BK 64
#define NT (NDIM / BK)

typedef __bf16 bf16x8 __attribute__((ext_vector_type(8)));
typedef float  f32x4  __attribute__((ext_vector_type(4)));

typedef __attribute__((address_space(1))) const unsigned char gu8;
typedef __attribute__((address_space(3))) unsigned char lu8;

__device__ inline unsigned short f2bf(float f) {
    union { float f; unsigned u; } cv; cv.f = f;
    unsigned u = cv.u;
    unsigned r = u + 0x7fffu + ((u >> 16) & 1u);  // round-to-nearest-even
    return (unsigned short)(r >> 16);
}

// ---------- Path A: prep (bf16 convert + norms), one wave per row ----------
__global__ __launch_bounds__(256) void rbf_prep(const float* __restrict__ X,
                                                const float* __restrict__ Y,
                                                unsigned short* __restrict__ Xb,
                                                unsigned short* __restrict__ Yb,
                                                float* __restrict__ x2,
                                                float* __restrict__ y2) {
    const int gw   = (blockIdx.x * blockDim.x + threadIdx.x) >> 6;  // 0..16383
    const int lane = threadIdx.x & 63;
    const float* src;
    unsigned short* dstb;
    float* dstn;
    int row;
    if (gw < MROWS) { src = X; dstb = Xb; dstn = x2; row = gw; }
    else            { src = Y; dstb = Yb; dstn = y2; row = gw - MROWS; }

    f32x4 v = *(const f32x4*)(src + (size_t)row * NDIM + lane * 4);
    ushort4 u;
    u.x = f2bf(v[0]); u.y = f2bf(v[1]); u.z = f2bf(v[2]); u.w = f2bf(v[3]);
    *(ushort4*)(dstb + (size_t)row * NDIM + lane * 4) = u;

    float s = v[0]*v[0] + v[1]*v[1] + v[2]*v[2] + v[3]*v[3];
#pragma unroll
    for (int off = 32; off > 0; off >>= 1) s += __shfl_xor(s, off);
    if (lane == 0) dstn[row] = s;
}

// ---------- Path A: bf16 GEMM + fused exp ----------
// 128x128 tile, 4 waves (2x2, 64x64 each), BK=64, double-buffered LDS,
// global_load_lds w/ pre-swizzled source (XOR (r&7) on 16B chunk index).
__global__ __launch_bounds__(256, 2) void rbf_gemm_bf16(
        const unsigned short* __restrict__ Xb,
        const unsigned short* __restrict__ Yb,
        const float* __restrict__ x2,
        const float* __restrict__ y2,
        float* __restrict__ out) {
    __shared__ unsigned short lds[2][2 * BM * BK];  // [buf][A(8192) | B(8192)]

    const int tid   = threadIdx.x;
    const int lane  = tid & 63;
    const int wid   = tid >> 6;
    const int wy    = wid >> 1;
    const int wx    = wid & 1;
    const int fr    = lane & 15;
    const int khalf = lane >> 4;

    // bijective XCD swizzle (nwg = 4096, divisible by 8)
    const int bid  = blockIdx.x;
    const int swz  = (bid & 7) * (4096 / 8) + (bid >> 3);
    const int row0 = (swz >> 6) * BM;
    const int col0 = (swz & 63) * BN;

    // staging constants: chunk t = p*256 + tid; r = t>>3; c = t&7
    const int rr  = tid >> 3;                 // 0..31 (row within 32-row pass)
    const int cc  = tid & 7;                  // 16B chunk within row
    const int sch = (cc ^ (rr & 7)) << 3;     // pre-swizzled source elem offset

    f32x4 acc[4][4] = {};

    auto stage = [&](int bu, int k0) {
        unsigned short* l = &lds[bu][0];
#pragma unroll
        for (int p = 0; p < 4; ++p) {
            const int r = p * 32 + rr;
            const unsigned short* sA = Xb + (size_t)(row0 + r) * NDIM + k0 + sch;
            const unsigned short* sB = Yb + (size_t)(col0 + r) * NDIM + k0 + sch;
            unsigned short* lA = l + (p * 256 + wid * 64) * 8;   // wave-uniform base
            unsigned short* lB = lA + BM * BK;
            __builtin_amdgcn_global_load_lds((gu8*)sA, (lu8*)lA, 16, 0, 0);
            __builtin_amdgcn_global_load_lds((gu8*)sB, (lu8*)lB, 16, 0, 0);
        }
    };

    stage(0, 0);
#pragma unroll
    for (int t = 0; t < NT; ++t) {
        if (t < NT - 1) {
            stage((t + 1) & 1, (t + 1) * BK);
            asm volatile("s_waitcnt vmcnt(8)" ::: "memory");  // current tile done
        } else {
            asm volatile("s_waitcnt vmcnt(0)" ::: "memory");
        }
        __builtin_amdgcn_s_barrier();
        asm volatile("" ::: "memory");

        const unsigned short* A = &lds[t & 1][0];
        const unsigned short* B = A + BM * BK;
#pragma unroll
        for (int kk = 0; kk < 2; ++kk) {
            bf16x8 af[4], bfv[4];
#pragma unroll
            for (int m = 0; m < 4; ++m) {
                const int r  = wy * 64 + m * 16 + fr;
                const int ch = (kk * 4 + khalf) ^ (r & 7);
                af[m] = *(const bf16x8*)(A + r * 64 + ch * 8);
            }
#pragma unroll
            for (int n = 0; n < 4; ++n) {
                const int r  = wx * 64 + n * 16 + fr;
                const int ch = (kk * 4 + khalf) ^ (r & 7);
                bfv[n] = *(const bf16x8*)(B + r * 64 + ch * 8);
            }
#pragma unroll
            for (int m = 0; m < 4; ++m)
#pragma unroll
                for (int n = 0; n < 4; ++n)
                    acc[m][n] = __builtin_amdgcn_mfma_f32_16x16x32_bf16(
                        af[m], bfv[n], acc[m][n], 0, 0, 0);
        }
        asm volatile("" ::: "memory");
        __builtin_amdgcn_s_barrier();
    }

    // epilogue: exp(-(x2 + y2 - 2*xy)); C/D: col=lane&15, row=(lane>>4)*4+reg
    const int ci    = row0 + wy * 64;
    const int cj    = col0 + wx * 64 + fr;
    const int rbase = khalf * 4;
#pragma unroll
    for (int m = 0; m < 4; ++m) {
#pragma unroll
        for (int r = 0; r < 4; ++r) {
            const int i  = ci + m * 16 + rbase + r;
            const float xi = x2[i];
#pragma unroll
            for (int n = 0; n < 4; ++n) {
                const int j = cj + n * 16;
                float sq = xi + y2[j] - 2.0f * acc[m][n][r];
                sq = fmaxf(sq, 0.0f);
                out[(size_t)i * MROWS + j] = __expf(-sq);
            }
        }
    }
}

// ---------- Path B: round-1 fallback (fp32 staging) ----------
__global__ __launch_bounds__(256) void rbf_norms(const float* __restrict__ X,
                                                 const float* __restrict__ Y,
                                                 float* __restrict__ x2,
                                                 float* __restrict__ y2) {
    const int gw   = (blockIdx.x * blockDim.x + threadIdx.x) >> 6;
    const int lane = threadIdx.x & 63;
    const float* src = (gw < MROWS) ? X : Y;
    float*       dst = (gw < MROWS) ? x2 : y2;
    const int    row = (gw < MROWS) ? gw : gw - MROWS;

    f32x4 v = *(const f32x4*)(src + (size_t)row * NDIM + lane * 4);
    float s = v[0]*v[0] + v[1]*v[1] + v[2]*v[2] + v[3]*v[3];
#pragma unroll
    for (int off = 32; off > 0; off >>= 1) s += __shfl_xor(s, off);
    if (lane == 0) dst[row] = s;
}

__global__ __launch_bounds__(256, 2) void rbf_gemm_f32(const float* __restrict__ X,
                                                       const float* __restrict__ Y,
                                                       const float* __restrict__ x2,
                                                       const float* __restrict__ y2,
                                                       float* __restrict__ out) {
    __shared__ unsigned short As[BM * BK];
    __shared__ unsigned short Bs[BN * BK];

    const int tid  = threadIdx.x;
    const int lane = tid & 63;
    const int wid  = tid >> 6;
    const int wy   = wid >> 1;
    const int wx   = wid & 1;

    const int row0 = blockIdx.y * BM;
    const int col0 = blockIdx.x * BN;

    f32x4 acc[4][4] = {};

    const int lrow = tid >> 4;
    const int lcol = (tid & 15) * 4;
    const int khalf = lane >> 4;
    const int fr    = lane & 15;

    for (int k0 = 0; k0 < NDIM; k0 += BK) {
#pragma unroll
        for (int p = 0; p < 8; ++p) {
            const int r = p * 16 + lrow;
            const int byte = r * (BK * 2) + lcol * 2;
            const int sw   = byte ^ ((r & 7) << 4);

            f32x4 va = *(const f32x4*)(X + (size_t)(row0 + r) * NDIM + k0 + lcol);
            ushort4 ua;
            ua.x = f2bf(va[0]); ua.y = f2bf(va[1]); ua.z = f2bf(va[2]); ua.w = f2bf(va[3]);
            *(ushort4*)((char*)As + sw) = ua;

            f32x4 vb = *(const f32x4*)(Y + (size_t)(col0 + r) * NDIM + k0 + lcol);
            ushort4 ub;
            ub.x = f2bf(vb[0]); ub.y = f2bf(vb[1]); ub.z = f2bf(vb[2]); ub.w = f2bf(vb[3]);
            *(ushort4*)((char*)Bs + sw) = ub;
        }
        __syncthreads();

#pragma unroll
        for (int kk = 0; kk < 2; ++kk) {
            bf16x8 af[4], bfr[4];
#pragma unroll
            for (int m = 0; m < 4; ++m) {
                const int r = wy * 64 + m * 16 + fr;
                const int byte = r * (BK * 2) + (kk * 32 + khalf * 8) * 2;
                af[m] = *(const bf16x8*)((const char*)As + (byte ^ ((r & 7) << 4)));
            }
#pragma unroll
            for (int n = 0; n < 4; ++n) {
                const int r = wx * 64 + n * 16 + fr;
                const int byte = r * (BK * 2) + (kk * 32 + khalf * 8) * 2;
                bfr[n] = *(const bf16x8*)((const char*)Bs + (byte ^ ((r & 7) << 4)));
            }
#pragma unroll
            for (int m = 0; m < 4; ++m)
#pragma unroll
                for (int n = 0; n < 4; ++n)
                    acc[m][n] = __builtin_amdgcn_mfma_f32_16x16x32_bf16(
                        af[m], bfr[n], acc[m][n], 0, 0, 0);
        }
        __syncthreads();
    }

    const int ci    = row0 + wy * 64;
    const int cj    = col0 + wx * 64 + fr;
    const int rbase = khalf * 4;
#pragma unroll
    for (int m = 0; m < 4; ++m) {
#pragma unroll
        for (int r = 0; r < 4; ++r) {
            const int i  = ci + m * 16 + rbase + r;
            const float xi = x2[i];
#pragma unroll
            for (int n = 0; n < 4; ++n) {
                const int j = cj + n * 16;
                float sq = xi + y2[j] - 2.0f * acc[m][n][r];
                sq = fmaxf(sq, 0.0f);
                out[(size_t)i * MROWS + j] = __expf(-sq);
            }
        }
    }
}

extern "C" void kernel_launch(void* const* d_in, const int* in_sizes, int n_in,
                              void* d_out, int out_size, void* d_ws, size_t ws_size,
                              hipStream_t stream) {
    const float* X = (const float*)d_in[0];
    const float* Y = (const float*)d_in[1];
    float* out = (float*)d_out;

    const size_t bf16_bytes = (size_t)2 * MROWS * NDIM * sizeof(unsigned short);  // 8 MiB
    const size_t need = bf16_bytes + (size_t)2 * MROWS * sizeof(float);

    if (ws_size >= need) {
        unsigned short* Xb = (unsigned short*)d_ws;
        unsigned short* Yb = Xb + (size_t)MROWS * NDIM;
        float* x2 = (float*)(Yb + (size_t)MROWS * NDIM);
        float* y2 = x2 + MROWS;

        rbf_prep<<<(2 * MROWS) / 4, 256, 0, stream>>>(X, Y, Xb, Yb, x2, y2);
        rbf_gemm_bf16<<<4096, 256, 0, stream>>>(Xb, Yb, x2, y2, out);
    } else {
        float* x2 = (float*)d_ws;
        float* y2 = x2 + MROWS;
        rbf_norms<<<(2 * MROWS) / 4, 256, 0, stream>>>(X, Y, x2, y2);
        dim3 grid(MROWS / BN, MROWS / BM);
        rbf_gemm_f32<<<grid, 256, 0, stream>>>(X, Y, x2, y2, out);
    }
}

// Round 3
// 81.215 us; speedup vs baseline: 1.7588x; 1.0476x over previous
//
#include <hip/hip_runtime.h>
#include <hip/hip_bf16.h>

// RBF Gram matrix: out[i][j] = exp(-||X_i - Y_j||^2), X,Y fp32 [8192][256].
// Path A: prep converts X,Y -> bf16 panels + fp32 norms; 256x256-tile bf16 MFMA
//   GEMM (8 waves, BK=64, dbuf LDS + counted vmcnt, global_load_lds with
//   pre-swizzled source), fused exp epilogue.
// Path B (ws too small): round-1 fp32-staging fallback.

#define MROWS 8192
#define NDIM  256
#define BM 256
#define BN 256
#define BK 64
#define NT (NDIM / BK)   // 4

typedef __bf16 bf16x8 __attribute__((ext_vector_type(8)));
typedef float  f32x4  __attribute__((ext_vector_type(4)));

typedef __attribute__((address_space(1))) const unsigned char gu8;
typedef __attribute__((address_space(3))) unsigned char lu8;

__device__ inline unsigned short f2bf(float f) {
    union { float f; unsigned u; } cv; cv.f = f;
    unsigned u = cv.u;
    unsigned r = u + 0x7fffu + ((u >> 16) & 1u);  // round-to-nearest-even
    return (unsigned short)(r >> 16);
}

// ---------- prep: bf16 convert + norms, one wave per row ----------
__global__ __launch_bounds__(256) void rbf_prep(const float* __restrict__ X,
                                                const float* __restrict__ Y,
                                                unsigned short* __restrict__ Xb,
                                                unsigned short* __restrict__ Yb,
                                                float* __restrict__ x2,
                                                float* __restrict__ y2) {
    const int gw   = (blockIdx.x * blockDim.x + threadIdx.x) >> 6;  // 0..16383
    const int lane = threadIdx.x & 63;
    const float* src;
    unsigned short* dstb;
    float* dstn;
    int row;
    if (gw < MROWS) { src = X; dstb = Xb; dstn = x2; row = gw; }
    else            { src = Y; dstb = Yb; dstn = y2; row = gw - MROWS; }

    f32x4 v = *(const f32x4*)(src + (size_t)row * NDIM + lane * 4);
    ushort4 u;
    u.x = f2bf(v[0]); u.y = f2bf(v[1]); u.z = f2bf(v[2]); u.w = f2bf(v[3]);
    *(ushort4*)(dstb + (size_t)row * NDIM + lane * 4) = u;

    float s = v[0]*v[0] + v[1]*v[1] + v[2]*v[2] + v[3]*v[3];
#pragma unroll
    for (int off = 32; off > 0; off >>= 1) s += __shfl_xor(s, off);
    if (lane == 0) dstn[row] = s;
}

// ---------- 256x256 bf16 GEMM + fused exp ----------
// 8 waves (2x4), per-wave 128x64 output. LDS: 2 bufs x (A 32KB + B 32KB).
// Staging: global_load_lds w=16, linear LDS dest, XOR-(r&7) pre-swizzled source.
__global__ __launch_bounds__(512, 2) void rbf_gemm256(
        const unsigned short* __restrict__ Xb,
        const unsigned short* __restrict__ Yb,
        const float* __restrict__ x2,
        const float* __restrict__ y2,
        float* __restrict__ out) {
    __shared__ unsigned short lds[2][2 * BM * BK];  // 128 KiB

    const int tid   = threadIdx.x;
    const int lane  = tid & 63;
    const int wid   = tid >> 6;     // 0..7
    const int wy    = wid >> 2;     // 0..1  (M-half)
    const int wx    = wid & 3;      // 0..3  (N-quarter)
    const int fr    = lane & 15;
    const int khalf = lane >> 4;

    // bijective XCD swizzle (nwg = 1024, divisible by 8)
    const int bid  = blockIdx.x;
    const int swz  = (bid & 7) * 128 + (bid >> 3);
    const int row0 = (swz >> 5) * BM;
    const int col0 = (swz & 31) * BN;

    // staging: chunk t = p*512 + tid; r = t>>3 = p*64 + (tid>>3); c = t&7.
    // r&7 == (tid>>3)&7 independent of p -> one swizzled source offset.
    const int rr  = tid >> 3;                 // 0..63
    const int cc  = tid & 7;
    const int sch = (cc ^ (rr & 7)) << 3;     // pre-swizzled elem offset in row

    f32x4 acc[8][4] = {};

    auto stage = [&](int bu, int k0) {
        unsigned short* l = &lds[bu][0];
#pragma unroll
        for (int p = 0; p < 4; ++p) {
            const int r = p * 64 + rr;
            const unsigned short* sA = Xb + (size_t)(row0 + r) * NDIM + k0 + sch;
            const unsigned short* sB = Yb + (size_t)(col0 + r) * NDIM + k0 + sch;
            unsigned short* lA = l + (p * 512 + wid * 64) * 8;  // wave-uniform base
            unsigned short* lB = lA + BM * BK;
            __builtin_amdgcn_global_load_lds((gu8*)sA, (lu8*)lA, 16, 0, 0);
            __builtin_amdgcn_global_load_lds((gu8*)sB, (lu8*)lB, 16, 0, 0);
        }
    };

    stage(0, 0);
    for (int t = 0; t < NT; ++t) {
        if (t < NT - 1) {
            stage((t + 1) & 1, (t + 1) * BK);
            asm volatile("s_waitcnt vmcnt(8)" ::: "memory");  // tile t staged
        } else {
            asm volatile("s_waitcnt vmcnt(0)" ::: "memory");
        }
        __builtin_amdgcn_s_barrier();
        asm volatile("" ::: "memory");

        const unsigned short* A = &lds[t & 1][0];
        const unsigned short* B = A + BM * BK;

        // B fragments once per tile, cached in regs across both m-halves
        bf16x8 bfv[4][2];
#pragma unroll
        for (int n = 0; n < 4; ++n)
#pragma unroll
            for (int kk = 0; kk < 2; ++kk) {
                const int r  = wx * 64 + n * 16 + fr;
                const int ch = (kk * 4 + khalf) ^ (r & 7);
                bfv[n][kk] = *(const bf16x8*)(B + r * 64 + ch * 8);
            }

#pragma unroll
        for (int half = 0; half < 2; ++half) {
            bf16x8 af[4][2];
#pragma unroll
            for (int m = 0; m < 4; ++m)
#pragma unroll
                for (int kk = 0; kk < 2; ++kk) {
                    const int r  = wy * 128 + (half * 4 + m) * 16 + fr;
                    const int ch = (kk * 4 + khalf) ^ (r & 7);
                    af[m][kk] = *(const bf16x8*)(A + r * 64 + ch * 8);
                }
            __builtin_amdgcn_s_setprio(1);
#pragma unroll
            for (int m = 0; m < 4; ++m)
#pragma unroll
                for (int n = 0; n < 4; ++n)
#pragma unroll
                    for (int kk = 0; kk < 2; ++kk)
                        acc[half * 4 + m][n] = __builtin_amdgcn_mfma_f32_16x16x32_bf16(
                            af[m][kk], bfv[n][kk], acc[half * 4 + m][n], 0, 0, 0);
            __builtin_amdgcn_s_setprio(0);
        }
        asm volatile("" ::: "memory");
        __builtin_amdgcn_s_barrier();
    }

    // epilogue: exp(-(x2 + y2 - 2*xy)); C/D: col=lane&15, row=(lane>>4)*4+reg
    const int ci    = row0 + wy * 128;
    const int cj    = col0 + wx * 64 + fr;
    const int rbase = khalf * 4;
    float yv[4];
#pragma unroll
    for (int n = 0; n < 4; ++n) yv[n] = y2[cj + n * 16];
#pragma unroll
    for (int m = 0; m < 8; ++m) {
#pragma unroll
        for (int rg = 0; rg < 4; ++rg) {
            const int i  = ci + m * 16 + rbase + rg;
            const float xi = x2[i];
#pragma unroll
            for (int n = 0; n < 4; ++n) {
                const int j = cj + n * 16;
                float sq = fmaxf(xi + yv[n] - 2.0f * acc[m][n][rg], 0.0f);
                out[(size_t)i * MROWS + j] = __expf(-sq);
            }
        }
    }
}

// ---------- Path B fallback: fp32 staging, 128x128 ----------
__global__ __launch_bounds__(256) void rbf_norms(const float* __restrict__ X,
                                                 const float* __restrict__ Y,
                                                 float* __restrict__ x2,
                                                 float* __restrict__ y2) {
    const int gw   = (blockIdx.x * blockDim.x + threadIdx.x) >> 6;
    const int lane = threadIdx.x & 63;
    const float* src = (gw < MROWS) ? X : Y;
    float*       dst = (gw < MROWS) ? x2 : y2;
    const int    row = (gw < MROWS) ? gw : gw - MROWS;

    f32x4 v = *(const f32x4*)(src + (size_t)row * NDIM + lane * 4);
    float s = v[0]*v[0] + v[1]*v[1] + v[2]*v[2] + v[3]*v[3];
#pragma unroll
    for (int off = 32; off > 0; off >>= 1) s += __shfl_xor(s, off);
    if (lane == 0) dst[row] = s;
}

__global__ __launch_bounds__(256, 2) void rbf_gemm_f32(const float* __restrict__ X,
                                                       const float* __restrict__ Y,
                                                       const float* __restrict__ x2,
                                                       const float* __restrict__ y2,
                                                       float* __restrict__ out) {
    __shared__ unsigned short As[128 * BK];
    __shared__ unsigned short Bs[128 * BK];

    const int tid  = threadIdx.x;
    const int lane = tid & 63;
    const int wid  = tid >> 6;
    const int wy   = wid >> 1;
    const int wx   = wid & 1;

    const int row0 = blockIdx.y * 128;
    const int col0 = blockIdx.x * 128;

    f32x4 acc[4][4] = {};

    const int lrow = tid >> 4;
    const int lcol = (tid & 15) * 4;
    const int khalf = lane >> 4;
    const int fr    = lane & 15;

    for (int k0 = 0; k0 < NDIM; k0 += BK) {
#pragma unroll
        for (int p = 0; p < 8; ++p) {
            const int r = p * 16 + lrow;
            const int byte = r * (BK * 2) + lcol * 2;
            const int sw   = byte ^ ((r & 7) << 4);

            f32x4 va = *(const f32x4*)(X + (size_t)(row0 + r) * NDIM + k0 + lcol);
            ushort4 ua;
            ua.x = f2bf(va[0]); ua.y = f2bf(va[1]); ua.z = f2bf(va[2]); ua.w = f2bf(va[3]);
            *(ushort4*)((char*)As + sw) = ua;

            f32x4 vb = *(const f32x4*)(Y + (size_t)(col0 + r) * NDIM + k0 + lcol);
            ushort4 ub;
            ub.x = f2bf(vb[0]); ub.y = f2bf(vb[1]); ub.z = f2bf(vb[2]); ub.w = f2bf(vb[3]);
            *(ushort4*)((char*)Bs + sw) = ub;
        }
        __syncthreads();

#pragma unroll
        for (int kk = 0; kk < 2; ++kk) {
            bf16x8 af[4], bfr[4];
#pragma unroll
            for (int m = 0; m < 4; ++m) {
                const int r = wy * 64 + m * 16 + fr;
                const int byte = r * (BK * 2) + (kk * 32 + khalf * 8) * 2;
                af[m] = *(const bf16x8*)((const char*)As + (byte ^ ((r & 7) << 4)));
            }
#pragma unroll
            for (int n = 0; n < 4; ++n) {
                const int r = wx * 64 + n * 16 + fr;
                const int byte = r * (BK * 2) + (kk * 32 + khalf * 8) * 2;
                bfr[n] = *(const bf16x8*)((const char*)Bs + (byte ^ ((r & 7) << 4)));
            }
#pragma unroll
            for (int m = 0; m < 4; ++m)
#pragma unroll
                for (int n = 0; n < 4; ++n)
                    acc[m][n] = __builtin_amdgcn_mfma_f32_16x16x32_bf16(
                        af[m], bfr[n], acc[m][n], 0, 0, 0);
        }
        __syncthreads();
    }

    const int ci    = row0 + wy * 64;
    const int cj    = col0 + wx * 64 + fr;
    const int rbase = khalf * 4;
#pragma unroll
    for (int m = 0; m < 4; ++m) {
#pragma unroll
        for (int r = 0; r < 4; ++r) {
            const int i  = ci + m * 16 + rbase + r;
            const float xi = x2[i];
#pragma unroll
            for (int n = 0; n < 4; ++n) {
                const int j = cj + n * 16;
                float sq = fmaxf(xi + y2[j] - 2.0f * acc[m][n][r], 0.0f);
                out[(size_t)i * MROWS + j] = __expf(-sq);
            }
        }
    }
}

extern "C" void kernel_launch(void* const* d_in, const int* in_sizes, int n_in,
                              void* d_out, int out_size, void* d_ws, size_t ws_size,
                              hipStream_t stream) {
    const float* X = (const float*)d_in[0];
    const float* Y = (const float*)d_in[1];
    float* out = (float*)d_out;

    const size_t bf16_bytes = (size_t)2 * MROWS * NDIM * sizeof(unsigned short);  // 8 MiB
    const size_t need = bf16_bytes + (size_t)2 * MROWS * sizeof(float);

    if (ws_size >= need) {
        unsigned short* Xb = (unsigned short*)d_ws;
        unsigned short* Yb = Xb + (size_t)MROWS * NDIM;
        float* x2 = (float*)(Yb + (size_t)MROWS * NDIM);
        float* y2 = x2 + MROWS;

        rbf_prep<<<(2 * MROWS) / 4, 256, 0, stream>>>(X, Y, Xb, Yb, x2, y2);
        rbf_gemm256<<<(MROWS / BM) * (MROWS / BN), 512, 0, stream>>>(Xb, Yb, x2, y2, out);
    } else {
        float* x2 = (float*)d_ws;
        float* y2 = x2 + MROWS;
        rbf_norms<<<(2 * MROWS) / 4, 256, 0, stream>>>(X, Y, x2, y2);
        dim3 grid(MROWS / 128, MROWS / 128);
        rbf_gemm_f32<<<grid, 256, 0, stream>>>(X, Y, x2, y2, out);
    }
}

// Round 4
// 79.554 us; speedup vs baseline: 1.7955x; 1.0209x over previous
//
#include <hip/hip_runtime.h>
#include <hip/hip_bf16.h>

// RBF Gram matrix: out[i][j] = exp(-||X_i - Y_j||^2), X,Y fp32 [8192][256].
// prep: X,Y -> bf16 panels + fp32 norms.
// gemm128: 128x128 tile, 4 waves, single-buffered 32KiB LDS -> 4 blocks/CU;
//   global_load_lds (pre-swizzled source), fused exp epilogue with LDS
//   transpose -> float4 coalesced stores (256B contiguous per 16-lane group).

#define MROWS 8192
#define NDIM  256
#define BM 128
#define BN 128
#define BK 64
#define NT (NDIM / BK)   // 4
#define EPS 68           // epilogue LDS row stride (dwords)

typedef __bf16 bf16x8 __attribute__((ext_vector_type(8)));
typedef float  f32x4  __attribute__((ext_vector_type(4)));

typedef __attribute__((address_space(1))) const unsigned char gu8;
typedef __attribute__((address_space(3))) unsigned char lu8;

__device__ inline unsigned short f2bf(float f) {
    union { float f; unsigned u; } cv; cv.f = f;
    unsigned u = cv.u;
    unsigned r = u + 0x7fffu + ((u >> 16) & 1u);  // round-to-nearest-even
    return (unsigned short)(r >> 16);
}

// ---------- prep: bf16 convert + norms, one wave per row ----------
__global__ __launch_bounds__(256) void rbf_prep(const float* __restrict__ X,
                                                const float* __restrict__ Y,
                                                unsigned short* __restrict__ Xb,
                                                unsigned short* __restrict__ Yb,
                                                float* __restrict__ x2,
                                                float* __restrict__ y2) {
    const int gw   = (blockIdx.x * blockDim.x + threadIdx.x) >> 6;  // 0..16383
    const int lane = threadIdx.x & 63;
    const float* src;
    unsigned short* dstb;
    float* dstn;
    int row;
    if (gw < MROWS) { src = X; dstb = Xb; dstn = x2; row = gw; }
    else            { src = Y; dstb = Yb; dstn = y2; row = gw - MROWS; }

    f32x4 v = *(const f32x4*)(src + (size_t)row * NDIM + lane * 4);
    ushort4 u;
    u.x = f2bf(v[0]); u.y = f2bf(v[1]); u.z = f2bf(v[2]); u.w = f2bf(v[3]);
    *(ushort4*)(dstb + (size_t)row * NDIM + lane * 4) = u;

    float s = v[0]*v[0] + v[1]*v[1] + v[2]*v[2] + v[3]*v[3];
#pragma unroll
    for (int off = 32; off > 0; off >>= 1) s += __shfl_xor(s, off);
    if (lane == 0) dstn[row] = s;
}

// ---------- 128x128 bf16 GEMM + fused exp, 4 blocks/CU ----------
__global__ __launch_bounds__(256, 4) void rbf_gemm128(
        const unsigned short* __restrict__ Xb,
        const unsigned short* __restrict__ Yb,
        const float* __restrict__ x2,
        const float* __restrict__ y2,
        float* __restrict__ out) {
    __shared__ __align__(16) unsigned short lds[2 * BM * BK];  // 32 KiB: A | B

    const int tid   = threadIdx.x;
    const int lane  = tid & 63;
    const int wid   = tid >> 6;     // 0..3
    const int wy    = wid >> 1;
    const int wx    = wid & 1;
    const int fr    = lane & 15;
    const int khalf = lane >> 4;

    // bijective XCD swizzle (nwg = 4096, divisible by 8)
    const int bid  = blockIdx.x;
    const int swz  = (bid & 7) * 512 + (bid >> 3);
    const int row0 = (swz >> 6) * BM;
    const int col0 = (swz & 63) * BN;

    // staging: per matrix 1024 chunks, 4 per thread. r = p*32 + (tid>>3).
    const int rr  = tid >> 3;                 // 0..31
    const int cc  = tid & 7;
    const int sch = (cc ^ (rr & 7)) << 3;     // pre-swizzled elem offset in row

    f32x4 acc[4][4] = {};

    for (int t = 0; t < NT; ++t) {
        const int k0 = t * BK;
        // ---- stage tile t (single buffer) ----
#pragma unroll
        for (int p = 0; p < 4; ++p) {
            const int r = p * 32 + rr;
            const unsigned short* sA = Xb + (size_t)(row0 + r) * NDIM + k0 + sch;
            const unsigned short* sB = Yb + (size_t)(col0 + r) * NDIM + k0 + sch;
            unsigned short* lA = lds + (p * 256 + wid * 64) * 8;  // wave-uniform base
            unsigned short* lB = lA + BM * BK;
            __builtin_amdgcn_global_load_lds((gu8*)sA, (lu8*)lA, 16, 0, 0);
            __builtin_amdgcn_global_load_lds((gu8*)sB, (lu8*)lB, 16, 0, 0);
        }
        asm volatile("s_waitcnt vmcnt(0)" ::: "memory");
        __builtin_amdgcn_s_barrier();
        asm volatile("" ::: "memory");

        const unsigned short* A = lds;
        const unsigned short* B = lds + BM * BK;
#pragma unroll
        for (int kk = 0; kk < 2; ++kk) {
            bf16x8 bfv[4];
#pragma unroll
            for (int n = 0; n < 4; ++n) {
                const int r  = wx * 64 + n * 16 + fr;
                const int ch = (kk * 4 + khalf) ^ (r & 7);
                bfv[n] = *(const bf16x8*)(B + r * 64 + ch * 8);
            }
            __builtin_amdgcn_s_setprio(1);
#pragma unroll
            for (int m = 0; m < 4; ++m) {
                const int r  = wy * 64 + m * 16 + fr;
                const int ch = (kk * 4 + khalf) ^ (r & 7);
                bf16x8 af = *(const bf16x8*)(A + r * 64 + ch * 8);
#pragma unroll
                for (int n = 0; n < 4; ++n)
                    acc[m][n] = __builtin_amdgcn_mfma_f32_16x16x32_bf16(
                        af, bfv[n], acc[m][n], 0, 0, 0);
            }
            __builtin_amdgcn_s_setprio(0);
        }
        asm volatile("" ::: "memory");
        __builtin_amdgcn_s_barrier();   // LDS free for restage / epilogue
    }

    // ---- epilogue: exp(-(x2 + y2 - 2*xy)), LDS transpose, float4 stores ----
    // C/D frag: col = lane&15 (+16n), row = khalf*4 + reg (+16m).
    float* ep = (float*)lds + wid * (16 * EPS);   // 4 waves x 4352 B, no overlap
    const int ci  = row0 + wy * 64;
    const int cjb = col0 + wx * 64;

    float yv[4];
#pragma unroll
    for (int n = 0; n < 4; ++n) yv[n] = y2[cjb + n * 16 + fr];

#pragma unroll
    for (int m = 0; m < 4; ++m) {
        // write phase: lane scatters its 16 exps into [row16][col64] (stride 68)
#pragma unroll
        for (int rg = 0; rg < 4; ++rg) {
            const int rl = khalf * 4 + rg;
            const float xi = x2[ci + m * 16 + rl];
#pragma unroll
            for (int n = 0; n < 4; ++n) {
                float sq = fmaxf(xi + yv[n] - 2.0f * acc[m][n][rg], 0.0f);
                ep[rl * EPS + n * 16 + fr] = __expf(-sq);
            }
        }
        asm volatile("s_waitcnt lgkmcnt(0)" ::: "memory");
        __builtin_amdgcn_sched_barrier(0);
        // read phase: float4 per lane -> 256B contiguous per 16-lane group
#pragma unroll
        for (int rowgrp = 0; rowgrp < 4; ++rowgrp) {
            const int rl = rowgrp * 4 + khalf;
            f32x4 v4 = *(const f32x4*)(ep + rl * EPS + fr * 4);
            const int i = ci + m * 16 + rl;
            *(f32x4*)(out + (size_t)i * MROWS + cjb + fr * 4) = v4;
        }
        asm volatile("s_waitcnt lgkmcnt(0)" ::: "memory");  // reads done before next m overwrites
        __builtin_amdgcn_sched_barrier(0);
    }
}

extern "C" void kernel_launch(void* const* d_in, const int* in_sizes, int n_in,
                              void* d_out, int out_size, void* d_ws, size_t ws_size,
                              hipStream_t stream) {
    const float* X = (const float*)d_in[0];
    const float* Y = (const float*)d_in[1];
    float* out = (float*)d_out;

    unsigned short* Xb = (unsigned short*)d_ws;
    unsigned short* Yb = Xb + (size_t)MROWS * NDIM;
    float* x2 = (float*)(Yb + (size_t)MROWS * NDIM);
    float* y2 = x2 + MROWS;

    rbf_prep<<<(2 * MROWS) / 4, 256, 0, stream>>>(X, Y, Xb, Yb, x2, y2);

    rbf_gemm128<<<(MROWS / BM) * (MROWS / BN), 256, 0, stream>>>(Xb, Yb, x2, y2, out);
}

// Round 5
// 67.886 us; speedup vs baseline: 2.1041x; 1.1719x over previous
//
#include <hip/hip_runtime.h>
#include <hip/hip_bf16.h>

// RBF Gram matrix: out[i][j] = exp(-||X_i - Y_j||^2), X,Y fp32 [8192][256].
// prep: X,Y -> bf16 panels + fp32 norms.
// gemm128: 128x128 tile, 4 waves, single-buffered 32KiB LDS, 4 blocks/CU;
//   global_load_lds (pre-swizzled source); per-XCD 8x8 super-block traversal
//   so panel reads stay L2-resident; direct-store exp epilogue (no LDS bounce).

#define MROWS 8192
#define NDIM  256
#define BM 128
#define BN 128
#define BK 64
#define NT (NDIM / BK)   // 4

typedef __bf16 bf16x8 __attribute__((ext_vector_type(8)));
typedef float  f32x4  __attribute__((ext_vector_type(4)));

typedef __attribute__((address_space(1))) const unsigned char gu8;
typedef __attribute__((address_space(3))) unsigned char lu8;

__device__ inline unsigned short f2bf(float f) {
    union { float f; unsigned u; } cv; cv.f = f;
    unsigned u = cv.u;
    unsigned r = u + 0x7fffu + ((u >> 16) & 1u);  // round-to-nearest-even
    return (unsigned short)(r >> 16);
}

// ---------- prep: bf16 convert + norms, one wave per row ----------
__global__ __launch_bounds__(256) void rbf_prep(const float* __restrict__ X,
                                                const float* __restrict__ Y,
                                                unsigned short* __restrict__ Xb,
                                                unsigned short* __restrict__ Yb,
                                                float* __restrict__ x2,
                                                float* __restrict__ y2) {
    const int gw   = (blockIdx.x * blockDim.x + threadIdx.x) >> 6;  // 0..16383
    const int lane = threadIdx.x & 63;
    const float* src;
    unsigned short* dstb;
    float* dstn;
    int row;
    if (gw < MROWS) { src = X; dstb = Xb; dstn = x2; row = gw; }
    else            { src = Y; dstb = Yb; dstn = y2; row = gw - MROWS; }

    f32x4 v = *(const f32x4*)(src + (size_t)row * NDIM + lane * 4);
    ushort4 u;
    u.x = f2bf(v[0]); u.y = f2bf(v[1]); u.z = f2bf(v[2]); u.w = f2bf(v[3]);
    *(ushort4*)(dstb + (size_t)row * NDIM + lane * 4) = u;

    float s = v[0]*v[0] + v[1]*v[1] + v[2]*v[2] + v[3]*v[3];
#pragma unroll
    for (int off = 32; off > 0; off >>= 1) s += __shfl_xor(s, off);
    if (lane == 0) dstn[row] = s;
}

// ---------- 128x128 bf16 GEMM + fused exp, 4 blocks/CU ----------
__global__ __launch_bounds__(256, 4) void rbf_gemm128(
        const unsigned short* __restrict__ Xb,
        const unsigned short* __restrict__ Yb,
        const float* __restrict__ x2,
        const float* __restrict__ y2,
        float* __restrict__ out) {
    __shared__ __align__(16) unsigned short lds[2 * BM * BK];  // 32 KiB: A | B

    const int tid   = threadIdx.x;
    const int lane  = tid & 63;
    const int wid   = tid >> 6;     // 0..3
    const int wy    = wid >> 1;
    const int wx    = wid & 1;
    const int fr    = lane & 15;
    const int khalf = lane >> 4;

    // per-XCD 8x8 super-block traversal (bijective over 4096 blocks):
    //   xcd = bid&7 owns row-tiles [xcd*8, xcd*8+8); within it, col-groups of 8
    //   are processed one after another (working set ~1MB -> L2-resident).
    const int bid  = blockIdx.x;
    const int xcd  = bid & 7;
    const int idx  = bid >> 3;          // 0..511
    const int sb   = idx >> 6;          // col-group 0..7
    const int r8   = (idx >> 3) & 7;    // row-tile within band
    const int c8   = idx & 7;           // col-tile within group
    const int row0 = (xcd * 8 + r8) * BM;
    const int col0 = (sb * 8 + c8) * BN;

    // staging: per matrix 1024 chunks, 4 per thread. r = p*32 + (tid>>3).
    const int rr  = tid >> 3;                 // 0..31
    const int cc  = tid & 7;
    const int sch = (cc ^ (rr & 7)) << 3;     // pre-swizzled elem offset in row

    f32x4 acc[4][4] = {};

    for (int t = 0; t < NT; ++t) {
        const int k0 = t * BK;
#pragma unroll
        for (int p = 0; p < 4; ++p) {
            const int r = p * 32 + rr;
            const unsigned short* sA = Xb + (size_t)(row0 + r) * NDIM + k0 + sch;
            const unsigned short* sB = Yb + (size_t)(col0 + r) * NDIM + k0 + sch;
            unsigned short* lA = lds + (p * 256 + wid * 64) * 8;  // wave-uniform base
            unsigned short* lB = lA + BM * BK;
            __builtin_amdgcn_global_load_lds((gu8*)sA, (lu8*)lA, 16, 0, 0);
            __builtin_amdgcn_global_load_lds((gu8*)sB, (lu8*)lB, 16, 0, 0);
        }
        asm volatile("s_waitcnt vmcnt(0)" ::: "memory");
        __builtin_amdgcn_s_barrier();
        asm volatile("" ::: "memory");

        const unsigned short* A = lds;
        const unsigned short* B = lds + BM * BK;
#pragma unroll
        for (int kk = 0; kk < 2; ++kk) {
            bf16x8 bfv[4];
#pragma unroll
            for (int n = 0; n < 4; ++n) {
                const int r  = wx * 64 + n * 16 + fr;
                const int ch = (kk * 4 + khalf) ^ (r & 7);
                bfv[n] = *(const bf16x8*)(B + r * 64 + ch * 8);
            }
            __builtin_amdgcn_s_setprio(1);
#pragma unroll
            for (int m = 0; m < 4; ++m) {
                const int r  = wy * 64 + m * 16 + fr;
                const int ch = (kk * 4 + khalf) ^ (r & 7);
                bf16x8 af = *(const bf16x8*)(A + r * 64 + ch * 8);
#pragma unroll
                for (int n = 0; n < 4; ++n)
                    acc[m][n] = __builtin_amdgcn_mfma_f32_16x16x32_bf16(
                        af, bfv[n], acc[m][n], 0, 0, 0);
            }
            __builtin_amdgcn_s_setprio(0);
        }
        if (t < NT - 1) {
            asm volatile("" ::: "memory");
            __builtin_amdgcn_s_barrier();   // LDS free for next stage
        }
    }

    // ---- epilogue: exp(-(x2 + y2 - 2*xy)), direct stores ----
    // C/D frag: col = lane&15 (+16n), row = khalf*4 + reg (+16m).
    const int ci = row0 + wy * 64;
    const int cj = col0 + wx * 64 + fr;
    float yv[4];
#pragma unroll
    for (int n = 0; n < 4; ++n) yv[n] = y2[cj + n * 16];
#pragma unroll
    for (int m = 0; m < 4; ++m) {
#pragma unroll
        for (int rg = 0; rg < 4; ++rg) {
            const int i  = ci + m * 16 + khalf * 4 + rg;
            const float xi = x2[i];
            float* orow = out + (size_t)i * MROWS + cj;
#pragma unroll
            for (int n = 0; n < 4; ++n) {
                float sq = fmaxf(xi + yv[n] - 2.0f * acc[m][n][rg], 0.0f);
                orow[n * 16] = __expf(-sq);
            }
        }
    }
}

extern "C" void kernel_launch(void* const* d_in, const int* in_sizes, int n_in,
                              void* d_out, int out_size, void* d_ws, size_t ws_size,
                              hipStream_t stream) {
    const float* X = (const float*)d_in[0];
    const float* Y = (const float*)d_in[1];
    float* out = (float*)d_out;

    unsigned short* Xb = (unsigned short*)d_ws;
    unsigned short* Yb = Xb + (size_t)MROWS * NDIM;
    float* x2 = (float*)(Yb + (size_t)MROWS * NDIM);
    float* y2 = x2 + MROWS;

    rbf_prep<<<(2 * MROWS) / 4, 256, 0, stream>>>(X, Y, Xb, Yb, x2, y2);

    rbf_gemm128<<<(MROWS / BM) * (MROWS / BN), 256, 0, stream>>>(Xb, Yb, x2, y2, out);
}

// Round 6
// 58.094 us; speedup vs baseline: 2.4588x; 1.1685x over previous
//
#include <hip/hip_runtime.h>
#include <hip/hip_bf16.h>

// RBF Gram matrix: out[i][j] = exp(-||X_i - Y_j||^2), X,Y fp32 [8192][256].
// prep: X,Y -> fp8 e4m3 panels (hand-rolled RNE) + fp32 norms.
// gemm128: 128x128 tile, 4 waves, BK=128 fp8 -> 32KiB single-buffer LDS,
//   4 blocks/CU; global_load_lds w=16 (pre-swizzled source); per-XCD 8x8
//   super-block traversal (L2-resident panels); fp8 MFMA; direct-store exp.

#define MROWS 8192
#define NDIM  256
#define BM 128
#define BN 128
#define BK 128
#define NT (NDIM / BK)   // 2

typedef float f32x4 __attribute__((ext_vector_type(4)));

typedef __attribute__((address_space(1))) const unsigned char gu8;
typedef __attribute__((address_space(3))) unsigned char lu8;

// fp32 -> OCP e4m3fn, RNE, saturating (no NaN inputs expected)
__device__ inline unsigned char f2e4m3(float f) {
    unsigned u = __float_as_uint(f);
    unsigned s = (u >> 24) & 0x80u;
    unsigned au = u & 0x7fffffffu;
    float a = __uint_as_float(au);
    if (a >= 448.0f) return (unsigned char)(s | 0x7E);
    if (a < 0.015625f) {                       // below normal min 2^-6
        float q = a * 512.0f;                  // grid of 2^-9
        int m = (int)rintf(q);                 // 0..8
        return (unsigned char)(s | (unsigned)m);  // m==8 -> 0x08 == 2^-6 normal
    }
    unsigned r = au + 0x7FFFFu + ((au >> 20) & 1u);   // RNE drop 20 bits
    int e = (int)(r >> 23) - 127;              // -6..8 after rounding
    unsigned m3 = (r >> 20) & 7u;
    return (unsigned char)(s | ((unsigned)(e + 7) << 3) | m3);
}

// ---------- prep: fp8 convert + fp32 norms, one wave per row ----------
__global__ __launch_bounds__(256) void rbf_prep(const float* __restrict__ X,
                                                const float* __restrict__ Y,
                                                unsigned char* __restrict__ Xb,
                                                unsigned char* __restrict__ Yb,
                                                float* __restrict__ x2,
                                                float* __restrict__ y2) {
    const int gw   = (blockIdx.x * blockDim.x + threadIdx.x) >> 6;  // 0..16383
    const int lane = threadIdx.x & 63;
    const float* src;
    unsigned char* dstb;
    float* dstn;
    int row;
    if (gw < MROWS) { src = X; dstb = Xb; dstn = x2; row = gw; }
    else            { src = Y; dstb = Yb; dstn = y2; row = gw - MROWS; }

    f32x4 v = *(const f32x4*)(src + (size_t)row * NDIM + lane * 4);
    uchar4 q;
    q.x = f2e4m3(v[0]); q.y = f2e4m3(v[1]); q.z = f2e4m3(v[2]); q.w = f2e4m3(v[3]);
    *(uchar4*)(dstb + (size_t)row * NDIM + lane * 4) = q;

    float ssum = v[0]*v[0] + v[1]*v[1] + v[2]*v[2] + v[3]*v[3];
#pragma unroll
    for (int off = 32; off > 0; off >>= 1) ssum += __shfl_xor(ssum, off);
    if (lane == 0) dstn[row] = ssum;
}

// ---------- 128x128 fp8 GEMM + fused exp, 4 blocks/CU ----------
__global__ __launch_bounds__(256, 4) void rbf_gemm128(
        const unsigned char* __restrict__ Xb,
        const unsigned char* __restrict__ Yb,
        const float* __restrict__ x2,
        const float* __restrict__ y2,
        float* __restrict__ out) {
    __shared__ __align__(16) unsigned char lds[2 * BM * BK];  // 32 KiB: A | B

    const int tid   = threadIdx.x;
    const int lane  = tid & 63;
    const int wid   = tid >> 6;     // 0..3
    const int wy    = wid >> 1;
    const int wx    = wid & 1;
    const int fr    = lane & 15;
    const int khalf = lane >> 4;    // 0..3

    // per-XCD 8x8 super-block traversal (bijective over 4096 blocks)
    const int bid  = blockIdx.x;
    const int xcd  = bid & 7;
    const int idx  = bid >> 3;          // 0..511
    const int sb   = idx >> 6;          // col-group 0..7
    const int r8   = (idx >> 3) & 7;
    const int c8   = idx & 7;
    const int row0 = (xcd * 8 + r8) * BM;
    const int col0 = (sb * 8 + c8) * BN;

    // staging: per matrix 16KB = 1024 x 16B chunks; 8 chunks per 128B row.
    // chunk t = p*256 + tid; r = t>>3 = p*32 + (tid>>3); c = t&7.
    const int rr  = tid >> 3;                 // 0..31
    const int cc  = tid & 7;
    const int sch = (cc ^ (rr & 7)) << 4;     // pre-swizzled byte offset in row

    f32x4 acc[4][4] = {};

    for (int t = 0; t < NT; ++t) {
        const int k0 = t * BK;
#pragma unroll
        for (int p = 0; p < 4; ++p) {
            const int r = p * 32 + rr;
            const unsigned char* sA = Xb + (size_t)(row0 + r) * NDIM + k0 + sch;
            const unsigned char* sB = Yb + (size_t)(col0 + r) * NDIM + k0 + sch;
            unsigned char* lA = lds + (p * 256 + wid * 64) * 16;  // wave-uniform base
            unsigned char* lB = lA + BM * BK;
            __builtin_amdgcn_global_load_lds((gu8*)sA, (lu8*)lA, 16, 0, 0);
            __builtin_amdgcn_global_load_lds((gu8*)sB, (lu8*)lB, 16, 0, 0);
        }
        asm volatile("s_waitcnt vmcnt(0)" ::: "memory");
        __builtin_amdgcn_s_barrier();
        asm volatile("" ::: "memory");

        const unsigned char* A = lds;
        const unsigned char* B = lds + BM * BK;
        const int j2 = khalf >> 1;          // chunk sub-index from khalf
        const int h8 = (khalf & 1) * 8;     // 8B half within chunk
#pragma unroll
        for (int s = 0; s < 4; ++s) {       // K=32 step within BK=128
            long bfv[4];
#pragma unroll
            for (int n = 0; n < 4; ++n) {
                const int r  = wx * 64 + n * 16 + fr;
                const int ch = (2 * s + j2) ^ (r & 7);
                bfv[n] = *(const long*)(B + r * BK + ch * 16 + h8);
            }
            __builtin_amdgcn_s_setprio(1);
#pragma unroll
            for (int m = 0; m < 4; ++m) {
                const int r  = wy * 64 + m * 16 + fr;
                const int ch = (2 * s + j2) ^ (r & 7);
                long af = *(const long*)(A + r * BK + ch * 16 + h8);
#pragma unroll
                for (int n = 0; n < 4; ++n)
                    acc[m][n] = __builtin_amdgcn_mfma_f32_16x16x32_fp8_fp8(
                        af, bfv[n], acc[m][n], 0, 0, 0);
            }
            __builtin_amdgcn_s_setprio(0);
        }
        if (t < NT - 1) {
            asm volatile("" ::: "memory");
            __builtin_amdgcn_s_barrier();   // LDS free for next stage
        }
    }

    // ---- epilogue: exp(-(x2 + y2 - 2*xy)), direct stores ----
    // C/D frag: col = lane&15 (+16n), row = khalf*4 + reg (+16m).
    const int ci = row0 + wy * 64;
    const int cj = col0 + wx * 64 + fr;
    float yv[4];
#pragma unroll
    for (int n = 0; n < 4; ++n) yv[n] = y2[cj + n * 16];
#pragma unroll
    for (int m = 0; m < 4; ++m) {
#pragma unroll
        for (int rg = 0; rg < 4; ++rg) {
            const int i  = ci + m * 16 + khalf * 4 + rg;
            const float xi = x2[i];
            float* orow = out + (size_t)i * MROWS + cj;
#pragma unroll
            for (int n = 0; n < 4; ++n) {
                float sq = fmaxf(xi + yv[n] - 2.0f * acc[m][n][rg], 0.0f);
                orow[n * 16] = __expf(-sq);
            }
        }
    }
}

extern "C" void kernel_launch(void* const* d_in, const int* in_sizes, int n_in,
                              void* d_out, int out_size, void* d_ws, size_t ws_size,
                              hipStream_t stream) {
    const float* X = (const float*)d_in[0];
    const float* Y = (const float*)d_in[1];
    float* out = (float*)d_out;

    unsigned char* Xb = (unsigned char*)d_ws;                 // 2 MiB
    unsigned char* Yb = Xb + (size_t)MROWS * NDIM;            // 2 MiB
    float* x2 = (float*)(Yb + (size_t)MROWS * NDIM);
    float* y2 = x2 + MROWS;

    rbf_prep<<<(2 * MROWS) / 4, 256, 0, stream>>>(X, Y, Xb, Yb, x2, y2);

    rbf_gemm128<<<(MROWS / BM) * (MROWS / BN), 256, 0, stream>>>(Xb, Yb, x2, y2, out);
}